// Round 1
// baseline (560.543 us; speedup 1.0000x reference)
//
#include <hip/hip_runtime.h>
#include <hip/hip_bf16.h>
#include <math.h>

#define TN 201
#define NSTEP 200
#define BATCH 4096
#define DIM 20
#define HID 128

// ws layout (floats):
//   [0..399]    M2 = -sqrt(LMBD) * A @ sigma^{-T}
//   [400..799]  M3 = -A @ sigma^{-T}
//   [800..999]  dt[200]
//   [1000..1199] sqrt(dt)[200]
//   [2048 ...]                nv  (TN*BATCH*20)
//   [2048+TN*BATCH*20 ...]    s   (NSTEP*BATCH*20)

__device__ __forceinline__ float fast_tanh(float x) {
  float cx = fminf(fmaxf(x, -15.f), 15.f);
  float e = __expf(2.f * cx);
  return __fdividef(e - 1.f, e + 1.f);
}

__global__ __launch_bounds__(256) void k0_setup(const float* __restrict__ ts,
                                                const float* __restrict__ sigma,
                                                const float* __restrict__ A,
                                                float* __restrict__ wsc) {
  __shared__ float aug[20][40];
  __shared__ float fac[20];
  __shared__ float piv;
  int tid = threadIdx.x;
  for (int e = tid; e < 800; e += 256) {
    int i = e / 40, j = e % 40;
    aug[i][j] = (j < 20) ? sigma[i * 20 + j] : ((j - 20) == i ? 1.f : 0.f);
  }
  __syncthreads();
  // Gauss-Jordan, no pivoting (sigma = I + 0.05*N, diagonally dominant)
  for (int p = 0; p < 20; ++p) {
    if (tid == 0) piv = 1.f / aug[p][p];
    __syncthreads();
    if (tid < 40) aug[p][tid] *= piv;
    __syncthreads();
    if (tid < 20) fac[tid] = aug[tid][p];
    __syncthreads();
    for (int e = tid; e < 800; e += 256) {
      int i = e / 40, j = e % 40;
      if (i != p) aug[i][j] -= fac[i] * aug[p][j];
    }
    __syncthreads();
  }
  // inv(sigma)[r][c] = aug[r][20+c];  SIT[k][j] = inv[j][k]
  // M2[i][j] = -sqrt(LMBD) * sum_k A[i][k] * aug[j][20+k]   (LMBD = 1)
  for (int e = tid; e < 400; e += 256) {
    int i = e / 20, j = e % 20;
    float acc = 0.f;
    for (int k = 0; k < 20; ++k) acc += A[i * 20 + k] * aug[j][20 + k];
    wsc[e] = -acc;          // M2
    wsc[400 + e] = -acc;    // M3 (identical since LMBD == 1)
  }
  if (tid < NSTEP) {
    float d = ts[tid + 1] - ts[tid];
    wsc[800 + tid] = d;
    wsc[1000 + tid] = sqrtf(d);
  }
}

__global__ __launch_bounds__(256) void k2_mlp_s(
    const float* __restrict__ states, const float* __restrict__ noises,
    const float* __restrict__ controls, const float* __restrict__ ts,
    const float* __restrict__ P, const float* __restrict__ W1,
    const float* __restrict__ b1, const float* __restrict__ W2,
    const float* __restrict__ b2, const float* __restrict__ wsc,
    float* __restrict__ nv_out, float* __restrict__ s_out) {
  __shared__ __align__(16) float sW1[21 * 128];
  __shared__ __align__(16) float sb1[128];
  __shared__ __align__(16) float sW2[128 * 20];
  __shared__ __align__(16) float sb2[24];
  __shared__ __align__(16) float sP[400];
  __shared__ __align__(16) float sM2[400];
  __shared__ __align__(16) float sM3[400];
  int tid = threadIdx.x;
  for (int e = tid; e < 21 * 128; e += 256) sW1[e] = W1[e];
  for (int e = tid; e < 128; e += 256) sb1[e] = b1[e];
  for (int e = tid; e < 128 * 20; e += 256) sW2[e] = W2[e];
  if (tid < 24) sb2[tid] = (tid < 20) ? b2[tid] : 0.f;
  for (int e = tid; e < 400; e += 256) {
    sP[e] = P[e];
    sM2[e] = wsc[e];
    sM3[e] = wsc[400 + e];
  }
  __syncthreads();

  int r = blockIdx.x * 256 + tid;  // r = t*BATCH + b; BATCH divisible by 256 -> t uniform per block
  int t = r >> 12;
  float tval = ts[t];

  const float4* xg = (const float4*)(states + (size_t)r * 20);
  float4 xv[5];
#pragma unroll
  for (int q = 0; q < 5; ++q) xv[q] = xg[q];

  float tx[21];
  tx[0] = tval;
#pragma unroll
  for (int q = 0; q < 5; ++q) {
    tx[1 + q * 4] = xv[q].x;
    tx[2 + q * 4] = xv[q].y;
    tx[3 + q * 4] = xv[q].z;
    tx[4 + q * 4] = xv[q].w;
  }

  float4 nv[5];
#pragma unroll
  for (int q = 0; q < 5; ++q) nv[q] = ((const float4*)sb2)[q];

  for (int kb = 0; kb < 32; ++kb) {
    float4 a = ((const float4*)sb1)[kb];
#pragma unroll
    for (int j = 0; j < 21; ++j) {
      float4 w = ((const float4*)(sW1 + j * 128))[kb];
      a.x += tx[j] * w.x;
      a.y += tx[j] * w.y;
      a.z += tx[j] * w.z;
      a.w += tx[j] * w.w;
    }
    float h0 = fast_tanh(a.x), h1 = fast_tanh(a.y), h2 = fast_tanh(a.z), h3 = fast_tanh(a.w);
    float hh[4] = {h0, h1, h2, h3};
#pragma unroll
    for (int c = 0; c < 4; ++c) {
      const float4* w2r = (const float4*)(sW2 + (kb * 4 + c) * 20);
      float hc = hh[c];
#pragma unroll
      for (int ib = 0; ib < 5; ++ib) {
        float4 w = w2r[ib];
        nv[ib].x += hc * w.x;
        nv[ib].y += hc * w.y;
        nv[ib].z += hc * w.z;
        nv[ib].w += hc * w.w;
      }
    }
  }

  float4* og = (float4*)(nv_out + (size_t)r * 20);
#pragma unroll
  for (int q = 0; q < 5; ++q) og[q] = nv[q];

  if (t < NSTEP) {
    float dtv = wsc[800 + t];
    float sqv = wsc[1000 + t];
    const float4* ng = (const float4*)(noises + (size_t)r * 20);
    const float4* cg = (const float4*)(controls + (size_t)r * 20);
    float4 nvv[5], cvv[5];
#pragma unroll
    for (int q = 0; q < 5; ++q) {
      nvv[q] = ng[q];
      cvv[q] = cg[q];
    }
    float sv[20];
#pragma unroll
    for (int i = 0; i < 20; ++i) {
      const float4* Pr = (const float4*)(sP + i * 20);
      const float4* M2r = (const float4*)(sM2 + i * 20);
      const float4* M3r = (const float4*)(sM3 + i * 20);
      float a1 = 0.f, a2 = 0.f, a3 = 0.f;
#pragma unroll
      for (int q = 0; q < 5; ++q) {
        float4 pw = Pr[q], w2 = M2r[q], w3 = M3r[q];
        float4 xq = xv[q], nq = nvv[q], cq = cvv[q];
        a1 += pw.x * xq.x + pw.y * xq.y + pw.z * xq.z + pw.w * xq.w;
        a2 += w2.x * nq.x + w2.y * nq.y + w2.z * nq.z + w2.w * nq.w;
        a3 += w3.x * cq.x + w3.y * cq.y + w3.z * cq.z + w3.w * cq.w;
      }
      sv[i] = dtv * a1 + sqv * a2 + dtv * a3;
    }
    float4* sg = (float4*)(s_out + (size_t)r * 20);
#pragma unroll
    for (int q = 0; q < 5; ++q) {
      float4 v;
      v.x = sv[q * 4 + 0];
      v.y = sv[q * 4 + 1];
      v.z = sv[q * 4 + 2];
      v.w = sv[q * 4 + 3];
      sg[q] = v;
    }
  }
}

// block: 320 threads = 16 batch-groups x 20 components
__global__ __launch_bounds__(320) void k3_scan(
    const float* __restrict__ states, const float* __restrict__ lw,
    const float* __restrict__ sigma, const float* __restrict__ Q,
    const float* __restrict__ nv_in, const float* __restrict__ s_in,
    float* __restrict__ out) {
  __shared__ float sST[400];  // sST[i*20+j] = sigma[j*20+i]  (sigma^T)
  __shared__ float sQ[400];
  __shared__ float sD[16][20];
  __shared__ float red[512];
  int tid = threadIdx.x;
  for (int e = tid; e < 400; e += 320) {
    int i = e / 20, j = e % 20;
    sST[e] = sigma[j * 20 + i];
    sQ[e] = Q[e];
  }
  for (int e = tid + 320; e < 512; e += 320) red[e] = 0.f;
  __syncthreads();

  int g = tid / 20, i = tid % 20;
  int b = blockIdx.x * 16 + g;

  // terminal_i = sum_j Q[i][j] * states[NSTEP][b][j]
  float term = 0.f;
  {
    const float* x200 = states + ((size_t)NSTEP * BATCH + b) * 20;
#pragma unroll
    for (int j = 0; j < 20; ++j) term += sQ[i * 20 + j] * x200[j];
  }

  float R = 0.f, acc = 0.f;
  float u = nv_in[((size_t)NSTEP * BATCH + b) * 20 + i];
  for (int t = NSTEP; t >= 0; --t) {
    float su = 0.f, un = 0.f;
    if (t > 0) {
      size_t base = ((size_t)(t - 1) * BATCH + b) * 20 + i;
      su = s_in[base];   // holds s_t (built from inputs at index t-1)
      un = nv_in[base];
    }
    float D = u - R - term;  // nv - lst
    sD[g][i] = D;
    __syncthreads();
    float y = 0.f;
#pragma unroll
    for (int j = 0; j < 20; ++j) y += sST[i * 20 + j] * sD[g][j];
    acc += y * y;
    __syncthreads();
    R += su;
    u = un;
  }

  float w = __expf(lw[b]);
  acc *= w * (1.f / ((float)TN * (float)BATCH));
  red[tid] = acc;
  __syncthreads();
  for (int s = 256; s > 0; s >>= 1) {
    if (tid < s) red[tid] += red[tid + s];
    __syncthreads();
  }
  if (tid == 0) atomicAdd(out, red[0]);
}

extern "C" void kernel_launch(void* const* d_in, const int* in_sizes, int n_in,
                              void* d_out, int out_size, void* d_ws, size_t ws_size,
                              hipStream_t stream) {
  const float* states = (const float*)d_in[0];
  const float* noises = (const float*)d_in[1];
  const float* controls = (const float*)d_in[2];
  const float* lw = (const float*)d_in[3];
  const float* ts = (const float*)d_in[4];
  const float* sigma = (const float*)d_in[5];
  const float* P = (const float*)d_in[6];
  const float* A = (const float*)d_in[7];
  const float* Q = (const float*)d_in[8];
  const float* W1 = (const float*)d_in[9];
  const float* b1 = (const float*)d_in[10];
  const float* W2 = (const float*)d_in[11];
  const float* b2 = (const float*)d_in[12];
  float* out = (float*)d_out;

  float* wsc = (float*)d_ws;
  float* nv = wsc + 2048;
  float* sbuf = nv + (size_t)TN * BATCH * 20;

  hipMemsetAsync(out, 0, sizeof(float), stream);
  hipLaunchKernelGGL(k0_setup, dim3(1), dim3(256), 0, stream, ts, sigma, A, wsc);
  hipLaunchKernelGGL(k2_mlp_s, dim3((TN * BATCH) / 256), dim3(256), 0, stream,
                     states, noises, controls, ts, P, W1, b1, W2, b2, wsc, nv, sbuf);
  hipLaunchKernelGGL(k3_scan, dim3(BATCH / 16), dim3(320), 0, stream,
                     states, lw, sigma, Q, nv, sbuf, out);
}

// Round 2
// 361.201 us; speedup vs baseline: 1.5519x; 1.5519x over previous
//
#include <hip/hip_runtime.h>
#include <math.h>

#define TN 201
#define NSTEP 200
#define BATCH 4096
#define DIM 20
#define HID 128

typedef __attribute__((ext_vector_type(8))) short short8;
typedef __attribute__((ext_vector_type(4))) float f32x4;

// ---------- helpers ----------
__device__ __forceinline__ unsigned short bfb(float f) {
  union { float f; unsigned u; } v; v.f = f;
  unsigned r = v.u + 0x7fffu + ((v.u >> 16) & 1u);  // RNE to bf16
  return (unsigned short)(r >> 16);
}
__device__ __forceinline__ unsigned pk2(float lo, float hi) {
  return (unsigned)bfb(lo) | ((unsigned)bfb(hi) << 16);
}
__device__ __forceinline__ float bfu(unsigned hs) {
  union { unsigned u; float f; } v; v.u = hs << 16; return v.f;
}
__device__ __forceinline__ float tanh_fast(float x) {
  float e = __expf(2.f * x);
  return 1.f - __fdividef(2.f, e + 1.f);
}
union S8U { short8 s; unsigned u[4]; };

// ws layout (floats):
//   [0..399]     Pp  = sigma^T P
//   [400..799]   Mp  = -sigma^T A sigma^{-T}
//   [800..1199]  Qp  = sigma^T Q
//   [1200..1399] dt[200]
//   [1400..1599] 1/sqrt(dt)[200]
//   [1600..1631] b2p = sigma^T b2 (padded to 32)
//   [2048..4607] W2p = W2 sigma  [128][20]
//   [8192 ... ]  z: uint per (t,b,i): lo16 = bf16(u~), hi16 = bf16(s~)

// ================= k0: setup =================
__global__ __launch_bounds__(256) void k0_setup(
    const float* __restrict__ ts, const float* __restrict__ sigma,
    const float* __restrict__ A, const float* __restrict__ P,
    const float* __restrict__ Q, const float* __restrict__ W2,
    const float* __restrict__ b2, float* __restrict__ wsc) {
  __shared__ float aug[20][40];
  __shared__ float sS[400], sA[400], sT1[400];
  __shared__ float fac[20];
  __shared__ float piv;
  int tid = threadIdx.x;
  for (int e = tid; e < 400; e += 256) { sS[e] = sigma[e]; sA[e] = A[e]; }
  for (int e = tid; e < 800; e += 256) {
    int i = e / 40, j = e % 40;
    aug[i][j] = (j < 20) ? sigma[i * 20 + j] : ((j - 20) == i ? 1.f : 0.f);
  }
  __syncthreads();
  for (int p = 0; p < 20; ++p) {
    if (tid == 0) piv = 1.f / aug[p][p];
    __syncthreads();
    if (tid < 40) aug[p][tid] *= piv;
    __syncthreads();
    if (tid < 20) fac[tid] = aug[tid][p];
    __syncthreads();
    for (int e = tid; e < 800; e += 256) {
      int i = e / 40, j = e % 40;
      if (i != p) aug[i][j] -= fac[i] * aug[p][j];
    }
    __syncthreads();
  }
  // T1[k][j] = sum_l A[k][l] * inv[j][l]   (A sigma^{-T})
  for (int e = tid; e < 400; e += 256) {
    int k = e / 20, j = e % 20;
    float s = 0.f;
    for (int l2 = 0; l2 < 20; ++l2) s += sA[k * 20 + l2] * aug[j][20 + l2];
    sT1[e] = s;
  }
  __syncthreads();
  for (int e = tid; e < 400; e += 256) {
    int i = e / 20, j = e % 20;
    float m = 0.f, pp = 0.f, qq = 0.f;
    for (int k = 0; k < 20; ++k) {
      float sk = sS[k * 20 + i];
      m += sk * sT1[k * 20 + j];
      pp += sk * P[k * 20 + j];
      qq += sk * Q[k * 20 + j];
    }
    wsc[e] = pp;
    wsc[400 + e] = -m;
    wsc[800 + e] = qq;
  }
  for (int e = tid; e < 2560; e += 256) {
    int h = e / 20, i = e % 20;
    float s = 0.f;
    for (int j = 0; j < 20; ++j) s += W2[h * 20 + j] * sS[j * 20 + i];
    wsc[2048 + e] = s;
  }
  if (tid < 32) {
    float s = 0.f;
    if (tid < 20)
      for (int j = 0; j < 20; ++j) s += b2[j] * sS[j * 20 + tid];
    wsc[1600 + tid] = s;
  }
  if (tid < NSTEP) {
    float d = ts[tid + 1] - ts[tid];
    wsc[1200 + tid] = d;
    wsc[1400 + tid] = rsqrtf(d);
  }
}

// ================= k2: MFMA MLP + integrand =================
// LDS map (dword offsets)
#define LWB1 0      // W1 B-frags  [nt(8)][lane64] x 16B  = 2048 dw
#define LWB2 2048   // W2p B-frags [kc(4)][nt2(2)][lane64] = 2048 dw
#define LWBS 4096   // Bs  B-frags [kc(2)][nt2(2)][lane64] = 1024 dw
#define LB1  5120   // b1 (128)
#define LB2P 5248   // b2p padded (32)
#define LXA  5280   // per-wave XA frag buf: 4 x 256 dw
#define LXS  6304   // per-wave XS frag buf: 4 x 512 dw
#define LHB  8352   // per-wave H buf: 4 x (16 rows x 36 dw) = 4 x 576
#define LTOT 10656  // 42624 B -> 3 blocks/CU by LDS

#define MFMA16(a, b, c) __builtin_amdgcn_mfma_f32_16x16x32_bf16((a), (b), (c), 0, 0, 0)

__global__ __launch_bounds__(256, 2) void k2_mfma(
    const float* __restrict__ states, const float* __restrict__ noises,
    const float* __restrict__ controls, const float* __restrict__ ts,
    const float* __restrict__ W1, const float* __restrict__ b1,
    const float* __restrict__ wsc, unsigned* __restrict__ zb) {
  __shared__ float lds[LTOT];
  const int tid = threadIdx.x;
  const int l = tid & 63;
  const int w = tid >> 6;
  const int quad = l >> 4;
  const int m16 = l & 15;

  const int r0 = blockIdx.x << 8;
  const int t = r0 >> 12;
  const bool has_s = (t < NSTEP);
  const float dtv = has_s ? wsc[1200 + t] : 0.f;
  const float ratio = has_s ? wsc[1400 + t] : 0.f;  // 1/sqrt(dt)
  const float tval = ts[t];

  // ---- build W1 B-frags: B[k][n] = W1[k*128+n], lane n=l&15, k=quad*8+j
  for (int s = tid; s < 512; s += 256) {
    int nt = s >> 6, l2 = s & 63;
    int q2 = l2 >> 4, n = (nt << 4) + (l2 & 15);
    unsigned d[4];
#pragma unroll
    for (int jj = 0; jj < 4; ++jj) {
      int k0 = (q2 << 3) + (jj << 1);
      float f0 = (k0 < 21) ? W1[k0 * HID + n] : 0.f;
      float f1 = (k0 + 1 < 21) ? W1[(k0 + 1) * HID + n] : 0.f;
      d[jj] = pk2(f0, f1);
    }
    *(uint4*)&lds[LWB1 + s * 4] = make_uint4(d[0], d[1], d[2], d[3]);
  }
  // ---- W2p B-frags
  for (int s = tid; s < 512; s += 256) {
    int kc = s >> 7, nt2 = (s >> 6) & 1, l2 = s & 63;
    int q2 = l2 >> 4, n = (nt2 << 4) + (l2 & 15);
    unsigned d[4];
#pragma unroll
    for (int jj = 0; jj < 4; ++jj) {
      int k0 = kc * 32 + (q2 << 3) + (jj << 1);
      float f0 = (n < 20) ? wsc[2048 + k0 * 20 + n] : 0.f;
      float f1 = (n < 20) ? wsc[2048 + (k0 + 1) * 20 + n] : 0.f;
      d[jj] = pk2(f0, f1);
    }
    *(uint4*)&lds[LWB2 + s * 4] = make_uint4(d[0], d[1], d[2], d[3]);
  }
  // ---- Bs B-frags: k<20 -> Pp[n][k]; 20..39 -> Mp[n][k-20]; 40..59 -> Mp[n][k-40]
  {
    int s = tid;
    int kc = s >> 7, nt2 = (s >> 6) & 1, l2 = s & 63;
    int q2 = l2 >> 4, n = (nt2 << 4) + (l2 & 15);
    unsigned d[4];
#pragma unroll
    for (int jj = 0; jj < 4; ++jj) {
      float f[2];
#pragma unroll
      for (int hh = 0; hh < 2; ++hh) {
        int k = kc * 32 + (q2 << 3) + (jj << 1) + hh;
        float v = 0.f;
        if (n < 20) {
          if (k < 20) v = wsc[n * 20 + k];
          else if (k < 40) v = wsc[400 + n * 20 + (k - 20)];
          else if (k < 60) v = wsc[400 + n * 20 + (k - 40)];
        }
        f[hh] = v;
      }
      d[jj] = pk2(f[0], f[1]);
    }
    *(uint4*)&lds[LWBS + s * 4] = make_uint4(d[0], d[1], d[2], d[3]);
  }
  if (tid < 128) lds[LB1 + tid] = b1[tid];
  if (tid >= 128 && tid < 160) {
    int i = tid - 128;
    lds[LB2P + i] = (i < 20) ? wsc[1600 + i] : 0.f;
  }

  // ---- per-thread row: pack [t, x0..x19, 0...] to bf16 dwords
  unsigned txd[16];
  {
    const float4* xg = (const float4*)(states + (size_t)(r0 + tid) * 20);
    float4 a0 = xg[0], a1 = xg[1], a2 = xg[2], a3 = xg[3], a4 = xg[4];
    float te[22];
    te[0] = tval;
    te[1] = a0.x; te[2] = a0.y; te[3] = a0.z; te[4] = a0.w;
    te[5] = a1.x; te[6] = a1.y; te[7] = a1.z; te[8] = a1.w;
    te[9] = a2.x; te[10] = a2.y; te[11] = a2.z; te[12] = a2.w;
    te[13] = a3.x; te[14] = a3.y; te[15] = a3.z; te[16] = a3.w;
    te[17] = a4.x; te[18] = a4.y; te[19] = a4.z; te[20] = a4.w;
    te[21] = 0.f;
#pragma unroll
    for (int d2 = 0; d2 < 11; ++d2) txd[d2] = pk2(te[2 * d2], te[2 * d2 + 1]);
#pragma unroll
    for (int d2 = 11; d2 < 16; ++d2) txd[d2] = 0u;
  }
  __syncthreads();

  // ---- load B-frags & biases to registers
  short8 W1f[8];
#pragma unroll
  for (int nt = 0; nt < 8; ++nt) W1f[nt] = *(short8*)&lds[LWB1 + (nt * 64 + l) * 4];
  short8 W2f0[4], W2f1[4];
#pragma unroll
  for (int kc = 0; kc < 4; ++kc) {
    W2f0[kc] = *(short8*)&lds[LWB2 + (kc * 128 + l) * 4];
    W2f1[kc] = *(short8*)&lds[LWB2 + (kc * 128 + 64 + l) * 4];
  }
  short8 Bs0[2], Bs1[2];
#pragma unroll
  for (int kc = 0; kc < 2; ++kc) {
    Bs0[kc] = *(short8*)&lds[LWBS + (kc * 128 + l) * 4];
    Bs1[kc] = *(short8*)&lds[LWBS + (kc * 128 + 64 + l) * 4];
  }
  float b1v[8];
#pragma unroll
  for (int nt = 0; nt < 8; ++nt) b1v[nt] = lds[LB1 + nt * 16 + m16];
  const float b2pv0 = lds[LB2P + m16];
  const float b2pv1 = lds[LB2P + 16 + m16];

  const int xa_base = LXA + w * 256;
  const int xs_base = LXS + w * 512;
  const int hb_base = LHB + w * 576;

  for (int mt = 0; mt < 4; ++mt) {
    // stage XA frag for this m-tile (owning lanes: quad == mt)
    if (quad == mt) {
#pragma unroll
      for (int q2 = 0; q2 < 4; ++q2)
        *(uint4*)&lds[xa_base + (q2 * 16 + m16) * 4] =
            make_uint4(txd[4 * q2], txd[4 * q2 + 1], txd[4 * q2 + 2], txd[4 * q2 + 3]);
    }
    short8 af = *(short8*)&lds[xa_base + l * 4];

    f32x4 acc20 = {b2pv0, b2pv0, b2pv0, b2pv0};
    f32x4 acc21 = {b2pv1, b2pv1, b2pv1, b2pv1};
#pragma unroll
    for (int p = 0; p < 4; ++p) {
      f32x4 aA = {b1v[2 * p], b1v[2 * p], b1v[2 * p], b1v[2 * p]};
      aA = MFMA16(af, W1f[2 * p], aA);
      f32x4 aB = {b1v[2 * p + 1], b1v[2 * p + 1], b1v[2 * p + 1], b1v[2 * p + 1]};
      aB = MFMA16(af, W1f[2 * p + 1], aB);
      // tanh + write H (row-major [m(16)][h'(32)], pitch 36 dw)
#pragma unroll
      for (int reg = 0; reg < 4; ++reg) {
        lds[hb_base + (quad * 4 + reg) * 36 + m16] = tanh_fast(aA[reg]);
        lds[hb_base + (quad * 4 + reg) * 36 + 16 + m16] = tanh_fast(aB[reg]);
      }
      // read back as layer-2 A-frag: H[m16][k = quad*8 + j]
      int rb = hb_base + m16 * 36 + quad * 8;
      float4 h0 = *(float4*)&lds[rb];
      float4 h1 = *(float4*)&lds[rb + 4];
      S8U hf;
      hf.u[0] = pk2(h0.x, h0.y); hf.u[1] = pk2(h0.z, h0.w);
      hf.u[2] = pk2(h1.x, h1.y); hf.u[3] = pk2(h1.z, h1.w);
      acc20 = MFMA16(hf.s, W2f0[p], acc20);
      acc21 = MFMA16(hf.s, W2f1[p], acc21);
    }

    // ---- integrand s~ via MFMA (K=64: [x | n/sqrt(dt) | c | 0])
    f32x4 as0 = {0.f, 0.f, 0.f, 0.f};
    f32x4 as1 = {0.f, 0.f, 0.f, 0.f};
    if (has_s) {
      const int rr = r0 + w * 64 + mt * 16 + m16;
      const float* xb = states + (size_t)rr * 20;
      const float* nb = noises + (size_t)rr * 20;
      const float* cb = controls + (size_t)rr * 20;
#pragma unroll
      for (int kc = 0; kc < 2; ++kc) {
        const float* pa; const float* pb; float sa, sb; bool lb;
        if (kc == 0) {
          if (quad == 0)      { pa = xb;      pb = xb + 4;  sa = 1.f;  sb = 1.f;   lb = true; }
          else if (quad == 1) { pa = xb + 8;  pb = xb + 12; sa = 1.f;  sb = 1.f;   lb = true; }
          else if (quad == 2) { pa = xb + 16; pb = nb;      sa = 1.f;  sb = ratio; lb = true; }
          else                { pa = nb + 4;  pb = nb + 8;  sa = ratio; sb = ratio; lb = true; }
        } else {
          if (quad == 0)      { pa = nb + 12; pb = nb + 16; sa = ratio; sb = ratio; lb = true; }
          else if (quad == 1) { pa = cb;      pb = cb + 4;  sa = 1.f;  sb = 1.f;   lb = true; }
          else if (quad == 2) { pa = cb + 8;  pb = cb + 12; sa = 1.f;  sb = 1.f;   lb = true; }
          else                { pa = cb + 16; pb = cb + 16; sa = 1.f;  sb = 0.f;   lb = false; }
        }
        float4 va = *(const float4*)pa;
        float4 vb = lb ? *(const float4*)pb : make_float4(0.f, 0.f, 0.f, 0.f);
        unsigned d0 = pk2(va.x * sa, va.y * sa);
        unsigned d1 = pk2(va.z * sa, va.w * sa);
        unsigned d2 = pk2(vb.x * sb, vb.y * sb);
        unsigned d3 = pk2(vb.z * sb, vb.w * sb);
        *(uint4*)&lds[xs_base + (kc * 64 + l) * 4] = make_uint4(d0, d1, d2, d3);
      }
#pragma unroll
      for (int kc = 0; kc < 2; ++kc) {
        short8 sf = *(short8*)&lds[xs_base + (kc * 64 + l) * 4];
        as0 = MFMA16(sf, Bs0[kc], as0);
        as1 = MFMA16(sf, Bs1[kc], as1);
      }
      as0 *= dtv;
      as1 *= dtv;
    }

    // ---- store packed (u~, s~) bf16 pairs
    const int rowb = r0 + w * 64 + mt * 16;
    {
      int dim = m16;  // nt2 = 0
#pragma unroll
      for (int reg = 0; reg < 4; ++reg) {
        int row = rowb + quad * 4 + reg;
        zb[(size_t)row * 20 + dim] = pk2(acc20[reg], as0[reg]);
      }
    }
    if (m16 < 4) {  // nt2 = 1, dims 16..19
      int dim = 16 + m16;
#pragma unroll
      for (int reg = 0; reg < 4; ++reg) {
        int row = rowb + quad * 4 + reg;
        zb[(size_t)row * 20 + dim] = pk2(acc21[reg], as1[reg]);
      }
    }
  }
}

// ================= k3: streaming suffix-sum + reduction =================
__global__ __launch_bounds__(128) void k3_stream(
    const float* __restrict__ states, const float* __restrict__ lw,
    const float* __restrict__ wsc, const unsigned* __restrict__ zb,
    float* __restrict__ out) {
  __shared__ float sQp[400];
  int tid = threadIdx.x;
  for (int e = tid; e < 400; e += 128) sQp[e] = wsc[800 + e];
  __syncthreads();

  const int u = blockIdx.x * 128 + tid;  // < 81920
  const int b = u / 20;
  const int i = u - b * 20;

  const float* xp = states + ((size_t)NSTEP * BATCH + b) * 20;
  float term = 0.f;
#pragma unroll
  for (int j = 0; j < 20; ++j) term = fmaf(sQp[i * 20 + j], xp[j], term);

  const size_t stride = (size_t)BATCH * DIM;  // 81920
  float R = 0.f, acc;
  {
    unsigned v = zb[(size_t)NSTEP * stride + u];
    R += bfu(v >> 16);  // stored 0
    float d = bfu(v & 0xffffu) - term - R;
    acc = d * d;
  }
  for (int tt = NSTEP - 1; tt >= 7; tt -= 8) {
    unsigned vv[8];
#pragma unroll
    for (int q = 0; q < 8; ++q) vv[q] = zb[(size_t)(tt - q) * stride + u];
#pragma unroll
    for (int q = 0; q < 8; ++q) {
      R += bfu(vv[q] >> 16);
      float d = bfu(vv[q] & 0xffffu) - term - R;
      acc = fmaf(d, d, acc);
    }
  }
  acc *= __expf(lw[b]) * (1.f / ((float)TN * (float)BATCH));
#pragma unroll
  for (int off = 32; off > 0; off >>= 1) acc += __shfl_down(acc, off, 64);
  if ((tid & 63) == 0) atomicAdd(out, acc);
}

extern "C" void kernel_launch(void* const* d_in, const int* in_sizes, int n_in,
                              void* d_out, int out_size, void* d_ws, size_t ws_size,
                              hipStream_t stream) {
  const float* states = (const float*)d_in[0];
  const float* noises = (const float*)d_in[1];
  const float* controls = (const float*)d_in[2];
  const float* lw = (const float*)d_in[3];
  const float* ts = (const float*)d_in[4];
  const float* sigma = (const float*)d_in[5];
  const float* P = (const float*)d_in[6];
  const float* A = (const float*)d_in[7];
  const float* Q = (const float*)d_in[8];
  const float* W1 = (const float*)d_in[9];
  const float* b1 = (const float*)d_in[10];
  const float* W2 = (const float*)d_in[11];
  const float* b2 = (const float*)d_in[12];
  float* out = (float*)d_out;

  float* wsc = (float*)d_ws;
  unsigned* zb = (unsigned*)(wsc + 8192);

  hipMemsetAsync(out, 0, sizeof(float), stream);
  hipLaunchKernelGGL(k0_setup, dim3(1), dim3(256), 0, stream,
                     ts, sigma, A, P, Q, W2, b2, wsc);
  hipLaunchKernelGGL(k2_mfma, dim3((TN * BATCH) / 256), dim3(256), 0, stream,
                     states, noises, controls, ts, W1, b1, wsc, zb);
  hipLaunchKernelGGL(k3_stream, dim3(BATCH * DIM / 128), dim3(128), 0, stream,
                     states, lw, wsc, zb, out);
}

// Round 3
// 287.976 us; speedup vs baseline: 1.9465x; 1.2543x over previous
//
#include <hip/hip_runtime.h>
#include <hip/hip_bf16.h>
#include <math.h>

#define TN 201
#define NSTEP 200
#define BATCH 4096
#define DIM 20
#define HID 128

typedef __attribute__((ext_vector_type(8))) short short8;
typedef __attribute__((ext_vector_type(4))) float f32x4;

union S8U { short8 s; unsigned u[4]; };

__device__ __forceinline__ unsigned pk2(float lo, float hi) {
  __hip_bfloat162 h = __float22bfloat162_rn(make_float2(lo, hi));
  union { __hip_bfloat162 h; unsigned u; } v;
  v.h = h;
  return v.u;
}
__device__ __forceinline__ float tanh_fast(float x) {
  float e = __builtin_amdgcn_exp2f(x * 2.8853900817779268f);
  return 1.f - 2.f * __builtin_amdgcn_rcpf(e + 1.f);
}

// ws layout (floats):
//   [0..399]     Pp  = sigma^T P
//   [400..799]   Mp  = -sigma^T A sigma^{-T}
//   [800..1199]  Qp  = sigma^T Q
//   [1200..1399] dt[200]
//   [1400..1599] 1/sqrt(dt)[200]
//   [1600..1631] b2p = sigma^T b2 (padded to 32, zeros beyond 20)
//   [2048..4607] W2p = W2 sigma  [128][20]
//   [8192 ...]   zc: A1[8][81920], A2[8][81920], S[8][81920]

// ================= k0: setup =================
__global__ __launch_bounds__(256) void k0_setup(
    const float* __restrict__ ts, const float* __restrict__ sigma,
    const float* __restrict__ A, const float* __restrict__ P,
    const float* __restrict__ Q, const float* __restrict__ W2,
    const float* __restrict__ b2, float* __restrict__ wsc) {
  __shared__ float aug[20][40];
  __shared__ float sS[400], sA[400], sT1[400];
  __shared__ float fac[20];
  __shared__ float piv;
  int tid = threadIdx.x;
  for (int e = tid; e < 400; e += 256) { sS[e] = sigma[e]; sA[e] = A[e]; }
  for (int e = tid; e < 800; e += 256) {
    int i = e / 40, j = e % 40;
    aug[i][j] = (j < 20) ? sigma[i * 20 + j] : ((j - 20) == i ? 1.f : 0.f);
  }
  __syncthreads();
  for (int p = 0; p < 20; ++p) {
    if (tid == 0) piv = 1.f / aug[p][p];
    __syncthreads();
    if (tid < 40) aug[p][tid] *= piv;
    __syncthreads();
    if (tid < 20) fac[tid] = aug[tid][p];
    __syncthreads();
    for (int e = tid; e < 800; e += 256) {
      int i = e / 40, j = e % 40;
      if (i != p) aug[i][j] -= fac[i] * aug[p][j];
    }
    __syncthreads();
  }
  // T1[k][j] = (A sigma^{-T})[k][j]
  for (int e = tid; e < 400; e += 256) {
    int k = e / 20, j = e % 20;
    float s = 0.f;
    for (int l2 = 0; l2 < 20; ++l2) s += sA[k * 20 + l2] * aug[j][20 + l2];
    sT1[e] = s;
  }
  __syncthreads();
  for (int e = tid; e < 400; e += 256) {
    int i = e / 20, j = e % 20;
    float m = 0.f, pp = 0.f, qq = 0.f;
    for (int k = 0; k < 20; ++k) {
      float sk = sS[k * 20 + i];
      m += sk * sT1[k * 20 + j];
      pp += sk * P[k * 20 + j];
      qq += sk * Q[k * 20 + j];
    }
    wsc[e] = pp;
    wsc[400 + e] = -m;
    wsc[800 + e] = qq;
  }
  for (int e = tid; e < 2560; e += 256) {
    int h = e / 20, i = e % 20;
    float s = 0.f;
    for (int j = 0; j < 20; ++j) s += W2[h * 20 + j] * sS[j * 20 + i];
    wsc[2048 + e] = s;
  }
  if (tid < 32) {
    float s = 0.f;
    if (tid < 20)
      for (int j = 0; j < 20; ++j) s += b2[j] * sS[j * 20 + tid];
    wsc[1600 + tid] = s;
  }
  if (tid < NSTEP) {
    float d = ts[tid + 1] - ts[tid];
    wsc[1200 + tid] = d;
    wsc[1400 + tid] = rsqrtf(d);
  }
}

// ================= kernel A: fused MLP + integrand + chunk scan =================
// per-wave LDS rows: tx pitch 26 (cols: [t, x0..x19, 0 x5]), xy pitch 42
// ([x0..x19, y0..y19, pad2]), H pitch 34 (32 cols). 1632 dw/wave.
#define TXP 26
#define XYP 42
#define HP 34
#define WLDS 1632

#define MFMA16(a, b, c) __builtin_amdgcn_mfma_f32_16x16x32_bf16((a), (b), (c), 0, 0, 0)

__global__ __launch_bounds__(256, 2) void kA(
    const float* __restrict__ states, const float* __restrict__ noises,
    const float* __restrict__ controls, const float* __restrict__ ts,
    const float* __restrict__ W1, const float* __restrict__ b1,
    const float* __restrict__ wsc, float* __restrict__ zc) {
  __shared__ float lds[4 * WLDS];
  const int tid = threadIdx.x;
  const int l = tid & 63;
  const int w = tid >> 6;
  const int quad = l >> 4;
  const int m16 = l & 15;

  const int c = blockIdx.x >> 6;    // 0..7 (chunk; c=0 = highest t)
  const int slab = blockIdx.x & 63; // 0..63
  const int b0 = slab * 64 + w * 16;
  const int thi = (c == 0) ? 200 : (174 - (c - 1) * 25);
  const int tlo = thi - ((c == 0) ? 25 : 24);

  const int twx = w * WLDS;
  const int xyb = twx + 16 * TXP;
  const int hb = xyb + 16 * XYP;

  // ---- zero tx pad cols 21..25 (16 rows x 5) ----
  for (int e = l; e < 80; e += 64) lds[twx + (e / 5) * TXP + 21 + e % 5] = 0.f;

  // ---- prologue: gather weight fragments into VGPRs ----
  short8 W1f[8];
#pragma unroll
  for (int nt = 0; nt < 8; ++nt) {
    S8U f;
    int n = nt * 16 + m16;
#pragma unroll
    for (int jj = 0; jj < 4; ++jj) {
      int k0 = quad * 8 + 2 * jj;
      float f0 = (k0 < 21) ? W1[k0 * HID + n] : 0.f;
      float f1 = (k0 + 1 < 21) ? W1[(k0 + 1) * HID + n] : 0.f;
      f.u[jj] = pk2(f0, f1);
    }
    W1f[nt] = f.s;
  }
  short8 W2f[4][2];
#pragma unroll
  for (int p = 0; p < 4; ++p)
#pragma unroll
    for (int nt2 = 0; nt2 < 2; ++nt2) {
      S8U f;
      int n = nt2 * 16 + m16;
      bool ok = (n < 20);
#pragma unroll
      for (int jj = 0; jj < 4; ++jj) {
        int k0 = p * 32 + quad * 8 + 2 * jj;
        float f0 = ok ? wsc[2048 + k0 * 20 + n] : 0.f;
        float f1 = ok ? wsc[2048 + (k0 + 1) * 20 + n] : 0.f;
        f.u[jj] = pk2(f0, f1);
      }
      W2f[p][nt2] = f.s;
    }
  short8 Bs[2][2];
#pragma unroll
  for (int nt2 = 0; nt2 < 2; ++nt2) {
    int n = nt2 * 16 + m16;
    bool ok = (n < 20);
    S8U f0v, f1v;
#pragma unroll
    for (int jj = 0; jj < 4; ++jj) {
      float v0 = 0.f, v1 = 0.f;
      int k0 = quad * 8 + 2 * jj;
      if (ok) {
        v0 = (k0 < 20) ? wsc[n * 20 + k0] : wsc[400 + n * 20 + (k0 - 20)];
        v1 = (k0 + 1 < 20) ? wsc[n * 20 + k0 + 1] : wsc[400 + n * 20 + (k0 + 1 - 20)];
      }
      f0v.u[jj] = pk2(v0, v1);
      float w0 = 0.f, w1 = 0.f;
      if (ok && quad == 0) {
        w0 = wsc[400 + n * 20 + 12 + 2 * jj];
        w1 = wsc[400 + n * 20 + 13 + 2 * jj];
      }
      f1v.u[jj] = pk2(w0, w1);
    }
    Bs[0][nt2] = f0v.s;
    Bs[1][nt2] = f1v.s;
  }
  float b1v[8];
#pragma unroll
  for (int nt = 0; nt < 8; ++nt) b1v[nt] = b1[nt * 16 + m16];
  const float b2pv0 = wsc[1600 + m16];
  const float b2pv1 = wsc[1616 + m16];

  // ---- invariant addresses ----
  int srowA[5], srowX[5];
#pragma unroll
  for (int it = 0; it < 5; ++it) {
    int idx = it * 64 + l;
    int row = idx / 20, col = idx - row * 20;
    srowA[it] = twx + row * TXP + 1 + col;
    srowX[it] = xyb + row * XYP + col;
  }
  const int rdTX = twx + m16 * TXP + quad * 8;
  const int rdXY = xyb + m16 * XYP + quad * 8;
  const int rdXY1 = xyb + m16 * XYP + 32;
  const int wrH = hb + quad * 4 * HP + m16;
  const int rdH = hb + m16 * HP + quad * 8;

  // ---- scan accumulators (C-layout) ----
  f32x4 A1a = {0.f, 0.f, 0.f, 0.f}, A1b = {0.f, 0.f, 0.f, 0.f};
  f32x4 A2a = {0.f, 0.f, 0.f, 0.f}, A2b = {0.f, 0.f, 0.f, 0.f};
  f32x4 La = {0.f, 0.f, 0.f, 0.f}, Lb = {0.f, 0.f, 0.f, 0.f};

  // ---- preload first t ----
  float xv[5], nv[5], cv[5];
  {
    size_t rb = ((size_t)thi * BATCH + b0) * 20;
#pragma unroll
    for (int it = 0; it < 5; ++it) {
      int idx = it * 64 + l;
      xv[it] = states[rb + idx];
      if (thi < 200) {
        nv[it] = noises[rb + idx];
        cv[it] = controls[rb + idx];
      }
    }
  }

#pragma unroll 1
  for (int t = thi; t >= tlo; --t) {
    // prefetch next t (t-1 <= 199 always, so noises/controls valid)
    float xn[5], nn[5], cn[5];
    if (t > tlo) {
      size_t rb = ((size_t)(t - 1) * BATCH + b0) * 20;
#pragma unroll
      for (int it = 0; it < 5; ++it) {
        int idx = it * 64 + l;
        xn[it] = states[rb + idx];
        nn[it] = noises[rb + idx];
        cn[it] = controls[rb + idx];
      }
    }
    const float tval = ts[t];
    const bool has_s = (t < 200);
    const float dtv = has_s ? wsc[1200 + t] : 0.f;
    const float rsd = has_s ? wsc[1400 + t] : 0.f;

    // ---- stage rows to LDS ----
#pragma unroll
    for (int it = 0; it < 5; ++it) {
      lds[srowA[it]] = xv[it];
      lds[srowX[it]] = xv[it];
      if (has_s) lds[srowX[it] + 20] = nv[it] * rsd + cv[it];
    }
    if (l < 16) lds[twx + l * TXP] = tval;

    // ---- XA fragment ----
    S8U af;
    if (quad < 3) {
#pragma unroll
      for (int jj = 0; jj < 4; ++jj) {
        float2 v = *(float2*)&lds[rdTX + 2 * jj];
        af.u[jj] = pk2(v.x, v.y);
      }
    } else {
      af.u[0] = af.u[1] = af.u[2] = af.u[3] = 0u;
    }

    // ---- MLP: layer1 -> tanh -> layer2 ----
    f32x4 u0 = {b2pv0, b2pv0, b2pv0, b2pv0};
    f32x4 u1 = {b2pv1, b2pv1, b2pv1, b2pv1};
#pragma unroll
    for (int p = 0; p < 4; ++p) {
      f32x4 aA = {b1v[2 * p], b1v[2 * p], b1v[2 * p], b1v[2 * p]};
      aA = MFMA16(af.s, W1f[2 * p], aA);
      f32x4 aB = {b1v[2 * p + 1], b1v[2 * p + 1], b1v[2 * p + 1], b1v[2 * p + 1]};
      aB = MFMA16(af.s, W1f[2 * p + 1], aB);
#pragma unroll
      for (int reg = 0; reg < 4; ++reg) {
        lds[wrH + reg * HP] = tanh_fast(aA[reg]);
        lds[wrH + reg * HP + 16] = tanh_fast(aB[reg]);
      }
      S8U hf;
#pragma unroll
      for (int jj = 0; jj < 4; ++jj) {
        float2 v = *(float2*)&lds[rdH + 2 * jj];
        hf.u[jj] = pk2(v.x, v.y);
      }
      u0 = MFMA16(hf.s, W2f[p][0], u0);
      u1 = MFMA16(hf.s, W2f[p][1], u1);
    }

    // ---- integrand s~ (K=40: [x | y]) ----
    f32x4 s0 = {0.f, 0.f, 0.f, 0.f}, s1 = {0.f, 0.f, 0.f, 0.f};
    if (has_s) {
      S8U sf0, sf1;
#pragma unroll
      for (int jj = 0; jj < 4; ++jj) {
        float2 v = *(float2*)&lds[rdXY + 2 * jj];
        sf0.u[jj] = pk2(v.x, v.y);
      }
      if (quad == 0) {
#pragma unroll
        for (int jj = 0; jj < 4; ++jj) {
          float2 v = *(float2*)&lds[rdXY1 + 2 * jj];
          sf1.u[jj] = pk2(v.x, v.y);
        }
      } else {
        sf1.u[0] = sf1.u[1] = sf1.u[2] = sf1.u[3] = 0u;
      }
      f32x4 a0 = {0.f, 0.f, 0.f, 0.f};
      f32x4 a1 = {0.f, 0.f, 0.f, 0.f};
      a0 = MFMA16(sf0.s, Bs[0][0], a0);
      a0 = MFMA16(sf1.s, Bs[1][0], a0);
      a1 = MFMA16(sf0.s, Bs[0][1], a1);
      a1 = MFMA16(sf1.s, Bs[1][1], a1);
      s0 = a0 * dtv;
      s1 = a1 * dtv;
    }

    // ---- scan update ----
    La += s0;
    Lb += s1;
    f32x4 p0 = u0 - La;
    f32x4 p1 = u1 - Lb;
    A2a += p0;
    A2b += p1;
    A1a += p0 * p0;
    A1b += p1 * p1;

    // rotate prefetch
#pragma unroll
    for (int it = 0; it < 5; ++it) {
      xv[it] = xn[it];
      nv[it] = nn[it];
      cv[it] = cn[it];
    }
  }

  // ---- epilogue stores ----
  float* zA1 = zc;
  float* zA2 = zc + (size_t)8 * BATCH * DIM;
  float* zS = zc + (size_t)16 * BATCH * DIM;
  const int bb = b0 + quad * 4;
#pragma unroll
  for (int reg = 0; reg < 4; ++reg) {
    size_t base = ((size_t)c * BATCH + (bb + reg)) * 20;
    zA1[base + m16] = A1a[reg];
    zA2[base + m16] = A2a[reg];
    zS[base + m16] = La[reg];
    if (m16 < 4) {
      zA1[base + 16 + m16] = A1b[reg];
      zA2[base + 16 + m16] = A2b[reg];
      zS[base + 16 + m16] = Lb[reg];
    }
  }
}

// ================= kernel B: combine chunks =================
__global__ __launch_bounds__(256) void kB(
    const float* __restrict__ states, const float* __restrict__ lw,
    const float* __restrict__ wsc, const float* __restrict__ zc,
    float* __restrict__ out) {
  __shared__ float sQp[400];
  int tid = threadIdx.x;
  for (int e = tid; e < 400; e += 256) sQp[e] = wsc[800 + e];
  __syncthreads();
  const int u = blockIdx.x * 256 + tid;  // < 81920
  const int b = u / 20;
  const int i = u - b * 20;
  const float* xp = states + ((size_t)NSTEP * BATCH + b) * 20;
  float term = 0.f;
#pragma unroll
  for (int j = 0; j < 20; ++j) term = fmaf(sQp[i * 20 + j], xp[j], term);

  const size_t CH = (size_t)BATCH * DIM;  // 81920
  float T = 0.f, obj = 0.f;
#pragma unroll
  for (int c = 0; c < 8; ++c) {
    float A1 = zc[(size_t)c * CH + u];
    float A2 = zc[(size_t)(8 + c) * CH + u];
    float S = zc[(size_t)(16 + c) * CH + u];
    float K = term + T;
    float nc = (c == 0) ? 26.f : 25.f;
    obj += A1 - 2.f * K * A2 + nc * K * K;
    T += S;
  }
  obj *= __expf(lw[b]) * (1.f / ((float)TN * (float)BATCH));
#pragma unroll
  for (int off = 32; off > 0; off >>= 1) obj += __shfl_down(obj, off, 64);
  if ((tid & 63) == 0) atomicAdd(out, obj);
}

extern "C" void kernel_launch(void* const* d_in, const int* in_sizes, int n_in,
                              void* d_out, int out_size, void* d_ws, size_t ws_size,
                              hipStream_t stream) {
  const float* states = (const float*)d_in[0];
  const float* noises = (const float*)d_in[1];
  const float* controls = (const float*)d_in[2];
  const float* lw = (const float*)d_in[3];
  const float* ts = (const float*)d_in[4];
  const float* sigma = (const float*)d_in[5];
  const float* P = (const float*)d_in[6];
  const float* A = (const float*)d_in[7];
  const float* Q = (const float*)d_in[8];
  const float* W1 = (const float*)d_in[9];
  const float* b1 = (const float*)d_in[10];
  const float* W2 = (const float*)d_in[11];
  const float* b2 = (const float*)d_in[12];
  float* out = (float*)d_out;

  float* wsc = (float*)d_ws;
  float* zc = wsc + 8192;

  hipMemsetAsync(out, 0, sizeof(float), stream);
  hipLaunchKernelGGL(k0_setup, dim3(1), dim3(256), 0, stream,
                     ts, sigma, A, P, Q, W2, b2, wsc);
  hipLaunchKernelGGL(kA, dim3(512), dim3(256), 0, stream,
                     states, noises, controls, ts, W1, b1, wsc, zc);
  hipLaunchKernelGGL(kB, dim3((BATCH * DIM) / 256), dim3(256), 0, stream,
                     states, lw, wsc, zc, out);
}